// Round 9
// baseline (1176.351 us; speedup 1.0000x reference)
//
#include <hip/hip_runtime.h>
#include <math.h>

// B=512, N=128, E=256, H=8, D=32. All fp32 (argmax fidelity requires it).
//
// Round-15: ONE structural change vs R14 (604us k_roll, absmax 0.0):
//  k_rollq drops sq_lds entirely. Since R14 the q table already lives in
//  global (qtab); per step each wave needs only 32 contiguous floats at a
//  WAVE-UNIFORM address (cur is uniform) -> read it directly from qtab via
//  readfirstlane(cur) (scalar/broadcast load, L2-hot, ~250cy ~ the LDS read
//  it replaces). LDS 157696 -> ~17KB, so the allocator's 2-blocks/CU target
//  (the same heuristic that pins VGPR=128) becomes ACHIEVABLE: 16 waves/CU,
//  4 waves/SIMD, ONE dispatch round instead of two. All arithmetic is
//  bit-identical (same qtab bits, same fma/sum order as R14).
//  Old k_roll kept verbatim as the use_qtab==0 fallback.

#define B_ 512
#define N_ 128
#define E_ 256
#define H_ 8
#define D_ 32
#define NEG (-1.0e9f)
#define CLIPV 10.0f
#define SCALE 0.17677669529663688110f  /* 1/sqrt(32), fp32-rounded */

typedef float v2f __attribute__((ext_vector_type(2)));

// packed fp32 FMA: acc.lo += a.lo*b.lo; acc.hi += a.hi*b.hi  (one VALU instr)
__device__ __forceinline__ void pkfma(v2f& acc, v2f a, v2f b) {
  asm("v_pk_fma_f32 %0, %1, %2, %0" : "+v"(acc) : "v"(a), "v"(b));
}

// ---------------- wave-wide reductions (64 lanes), LDS-free ----------------
template <int CTRL>
__device__ __forceinline__ float dpp_f(float x) {
  int r = __builtin_amdgcn_update_dpp(__float_as_int(x), __float_as_int(x),
                                      CTRL, 0xf, 0xf, false);
  return __int_as_float(r);
}
template <int CTRL, int RM>
__device__ __forceinline__ float dpp_mv(float x, float idv) {
  int r = __builtin_amdgcn_update_dpp(__float_as_int(idv), __float_as_int(x),
                                      CTRL, RM, 0xf, false);
  return __int_as_float(r);
}
__device__ __forceinline__ float wred_max(float v) {
  v = fmaxf(v, dpp_f<0xB1>(v));                       // xor 1 (quad_perm)
  v = fmaxf(v, dpp_f<0x4E>(v));                       // xor 2 (quad_perm)
  v = fmaxf(v, dpp_f<0x124>(v));                      // row_ror:4
  v = fmaxf(v, dpp_f<0x128>(v));                      // row_ror:8 -> row totals
  v = fmaxf(v, dpp_mv<0x142, 0xa>(v, -1e38f));        // bcast15 -> rows 1,3
  v = fmaxf(v, dpp_mv<0x143, 0xc>(v, -1e38f));        // bcast31 -> rows 2,3
  return __int_as_float(__builtin_amdgcn_readlane(__float_as_int(v), 63));
}
__device__ __forceinline__ float wred_sum(float v) {
  v += dpp_f<0xB1>(v);
  v += dpp_f<0x4E>(v);
  v += dpp_f<0x124>(v);
  v += dpp_f<0x128>(v);
  v += dpp_mv<0x142, 0xa>(v, 0.0f);
  v += dpp_mv<0x143, 0xc>(v, 0.0f);
  return __int_as_float(__builtin_amdgcn_readlane(__float_as_int(v), 63));
}

// ---------------------------------------------------------------- K0: weight folds
__global__ void k0_prep(const float* __restrict__ Wqkv, const float* __restrict__ bqkv,
                        const float* __restrict__ Wmlp, const float* __restrict__ bmlp,
                        float* __restrict__ Wc, float* __restrict__ bc,
                        float* __restrict__ wc2, float* __restrict__ cconst) {
  int t = threadIdx.x;
  int blk = blockIdx.x;
  __shared__ float row_s[E_];
  if (blk < E_) {
    int g = blk;
    row_s[t] = Wqkv[g * 768 + 512 + t];
    __syncthreads();
    int f = t;
    const float4* wm4 = (const float4*)(Wmlp + f * E_);
    const float4* w34 = (const float4*)row_s;
    float acc = 0.f;
#pragma unroll 8
    for (int j = 0; j < E_ / 4; ++j) {
      float4 a = w34[j]; float4 bv = wm4[j];
      acc += a.x * bv.x + a.y * bv.y + a.z * bv.z + a.w * bv.w;
    }
    Wc[g * E_ + f] = acc;
  } else {
    int f = t;
    float a1 = 0.f, a2 = 0.f;
    for (int e = 0; e < E_; ++e) {
      a1 += bqkv[512 + e] * Wmlp[f * E_ + e];
      a2 += Wqkv[f * 768 + 512 + e] * bmlp[e];
    }
    bc[f] = a1;
    wc2[f] = a2;
    if (t == 0) {
      float c = 0.f;
      for (int e = 0; e < E_; ++e) c += bqkv[512 + e] * bmlp[e];
      *cconst = c;
    }
  }
}

// ---------------------------------------------------------------- K1: precompute GEMM (up to 4 tensors)
__global__ __launch_bounds__(256, 2)
void k_gemm(const float* __restrict__ emb, const float* __restrict__ Wqkv,
            const float* __restrict__ bqkv,
            const float* __restrict__ Wc, const float* __restrict__ bc,
            const float* __restrict__ Wstep, const float* __restrict__ qbase,
            float* __restrict__ kk_, float* __restrict__ vv_,
            float* __restrict__ lk2, float* __restrict__ qtab,
            int ncc, int tmask) {
  __shared__ float As[256 * 64];  // [kk][m], exactly 64 KiB
  int t = threadIdx.x;
  int r0 = blockIdx.x * 64;
  {
    int m = t >> 2;
    int c0 = t & 3;
    const float4* e4 = (const float4*)emb;
#pragma unroll
    for (int p = 0; p < 16; ++p) {
      int c4 = c0 + p * 4;
      float4 a = e4[(size_t)(r0 + m) * 64 + c4];
      As[(c4 * 4 + 0) * 64 + m] = a.x;
      As[(c4 * 4 + 1) * 64 + m] = a.y;
      As[(c4 * 4 + 2) * 64 + m] = a.z;
      As[(c4 * 4 + 3) * 64 + m] = a.w;
    }
  }
  __syncthreads();
  int tx = t & 15, ty = t >> 4;
  const float4* As4 = (const float4*)As;
  for (int cc = 0; cc < ncc; ++cc) {
    const float* Bp; int ldb4; const float* bias; float* outp;
    int colbase = (cc & 1) * 128;
    switch (cc >> 1) {
      case 0:  Bp = Wqkv + colbase;          ldb4 = 192; bias = bqkv + colbase;       outp = kk_; break;
      case 1:  Bp = Wqkv + 256 + colbase;    ldb4 = 192; bias = bqkv + 256 + colbase; outp = vv_; break;
      case 2:  Bp = Wc + colbase;            ldb4 = 64;  bias = bc + colbase;         outp = lk2; break;
      default: Bp = Wstep + 65536 + colbase; ldb4 = 64;
               bias = qbase + (size_t)(r0 >> 7) * 256 + colbase;                      outp = qtab; break;
    }
    const float4* B4 = (const float4*)Bp;
    float acc[4][8];
#pragma unroll
    for (int i = 0; i < 4; ++i)
#pragma unroll
      for (int j = 0; j < 8; ++j) acc[i][j] = 0.f;

#pragma unroll 4
    for (int kk = 0; kk < 256; ++kk) {
      float4 b0 = B4[kk * ldb4 + tx * 2];
      float4 b1 = B4[kk * ldb4 + tx * 2 + 1];
      float4 av = As4[kk * 16 + ty];
      float a_[4] = {av.x, av.y, av.z, av.w};
#pragma unroll
      for (int i = 0; i < 4; ++i) {
        acc[i][0] += a_[i] * b0.x; acc[i][1] += a_[i] * b0.y;
        acc[i][2] += a_[i] * b0.z; acc[i][3] += a_[i] * b0.w;
        acc[i][4] += a_[i] * b1.x; acc[i][5] += a_[i] * b1.y;
        acc[i][6] += a_[i] * b1.z; acc[i][7] += a_[i] * b1.w;
      }
    }
    float bj[8];
#pragma unroll
    for (int j = 0; j < 8; ++j) bj[j] = bias ? bias[tx * 8 + j] : 0.f;
    int tr = (tmask >> (cc >> 1)) & 1;
    if (!tr) {
#pragma unroll
      for (int i = 0; i < 4; ++i) {
        int row = r0 + ty * 4 + i;
        float4 o0 = make_float4(acc[i][0] + bj[0], acc[i][1] + bj[1], acc[i][2] + bj[2], acc[i][3] + bj[3]);
        float4 o1 = make_float4(acc[i][4] + bj[4], acc[i][5] + bj[5], acc[i][6] + bj[6], acc[i][7] + bj[7]);
        float4* o4 = (float4*)(outp + (size_t)row * 256 + colbase + tx * 8);
        o4[0] = o0; o4[1] = o1;
      }
    } else {
#pragma unroll
      for (int i = 0; i < 4; ++i) {
        int row = r0 + ty * 4 + i;
        int bb = row >> 7, nn = row & 127;
        float* op = outp + (size_t)bb * 32768 + nn;
#pragma unroll
        for (int j = 0; j < 8; ++j)
          op[(size_t)(colbase + tx * 8 + j) * 128] = acc[i][j] + bj[j];
      }
    }
  }
}

// ---------------------------------------------------------------- K2: qbase per b
__global__ void k_qbase(const float* __restrict__ emb, const float* __restrict__ Wfix,
                        const float* __restrict__ bfix, const float* __restrict__ Wstep,
                        const float* __restrict__ bstep, float* __restrict__ qbase) {
  int b = blockIdx.x, t = threadIdx.x;
  __shared__ float ge[E_], fi[E_];
  const float* eb = emb + (size_t)b * N_ * E_;
  float s = 0.f;
#pragma unroll 8
  for (int n = 0; n < N_; ++n) s += eb[n * E_ + t];
  ge[t] = s * (1.0f / 128.0f);
  fi[t] = eb[t];
  __syncthreads();
  float acc = bfix[t] + bstep[t];
#pragma unroll 4
  for (int g = 0; g < E_; ++g)
    acc += ge[g] * Wfix[g * E_ + t] + fi[g] * Wstep[g * E_ + t];
  qbase[b * E_ + t] = acc;
}

// ---------------------------------------------------------------- K3: c[b,n]
__global__ void k_c(const float* __restrict__ emb, const float* __restrict__ wc2,
                    const float* __restrict__ cconst, float* __restrict__ cvec) {
  __shared__ float w[E_];
  int t = threadIdx.x;
  w[t] = wc2[t];
  __syncthreads();
  int row = blockIdx.x * 256 + t;
  const float4* e4 = (const float4*)(emb + (size_t)row * E_);
  const float4* w4 = (const float4*)w;
  float acc = 0.f;
#pragma unroll 8
  for (int j = 0; j < E_ / 4; ++j) {
    float4 a = e4[j], bv = w4[j];
    acc += a.x * bv.x + a.y * bv.y + a.z * bv.z + a.w * bv.w;
  }
  cvec[row] = acc + *cconst;
}

// ---------------------------------------------------------------- K4a: rollout, q from global qtab
// One block (512 thr, 8 waves) per b. LDS ~17KB -> 2 blocks/CU (4 waves/SIMD),
// one dispatch round. Loop arithmetic VERBATIM R14.
__global__ __launch_bounds__(512)
void k_rollq(const float* __restrict__ kT, const float* __restrict__ vv_,
             const float* __restrict__ lkT, const float* __restrict__ cvec,
             const float* __restrict__ qtab, float* __restrict__ out) {
  int lt = threadIdx.x;
  int b = blockIdx.x;
  int h = lt >> 6;      // wave = head
  int j = lt & 63;      // lane

  __shared__ float work[4352];          // 17 KiB: at_s | ctx_s | zp
  float* at_s  = work;                  // [8][128] wave-private slices
  float* ctx_s = work + 1024;           // [8][32]  wave-private slices
  float* zp    = work + 1280;           // [2][128 rows x stride 12] z partials

  // ---- register fills as v2f pairs (coalesced within 32/64-lane groups) ----
  const float* kTb = kT + (size_t)b * 32768;
  const float* vb  = vv_ + (size_t)b * 32768;
  const float* lTb = lkT + (size_t)b * 32768;

  v2f k0p[16], k1p[16];       // k[h][2d..2d+1][j], k[h][..][j+64]
#pragma unroll
  for (int d = 0; d < 16; ++d) {
    k0p[d] = (v2f){kTb[(h * 32 + 2 * d) * 128 + j],      kTb[(h * 32 + 2 * d + 1) * 128 + j]};
    k1p[d] = (v2f){kTb[(h * 32 + 2 * d) * 128 + j + 64], kTb[(h * 32 + 2 * d + 1) * 128 + j + 64]};
    asm("" : "+v"(k0p[d]));
    asm("" : "+v"(k1p[d]));
  }
  int e_own = h * 32 + (j & 31), nh = j >> 5;
  v2f vp[32];                 // v[nh*64+2m..2m+1][e_own]
#pragma unroll
  for (int m = 0; m < 32; ++m) {
    vp[m] = (v2f){vb[(nh * 64 + 2 * m) * 256 + e_own], vb[(nh * 64 + 2 * m + 1) * 256 + e_own]};
    asm("" : "+v"(vp[m]));
  }
  v2f l0p[16], l1p[16];       // lk2[j][h-slice pairs], lk2[j+64][...]
#pragma unroll
  for (int e = 0; e < 16; ++e) {
    l0p[e] = (v2f){lTb[(h * 32 + 2 * e) * 128 + j],      lTb[(h * 32 + 2 * e + 1) * 128 + j]};
    l1p[e] = (v2f){lTb[(h * 32 + 2 * e) * 128 + j + 64], lTb[(h * 32 + 2 * e + 1) * 128 + j + 64]};
    asm("" : "+v"(l0p[e]));
    asm("" : "+v"(l1p[e]));
  }
  float cv_lo = cvec[b * 128 + j];
  float cv_hi = cvec[b * 128 + j + 64];
  int vis_lo = (j == 0) ? 1 : 0, vis_hi = 0;
  int cur = 0;
  float lp = 0.f;
  int rof0 = j * 12;
  int rof1 = rof0 + 768;      // (j+64)*12
  int csw  = h ^ ((j >> 2) & 7);
  const float* qhb = qtab + ((size_t)b << 15) + (h << 5);  // + cur*256 per step

#pragma unroll 1
  for (int it = 0; it < N_ - 1; ++it) {
    // --- scores (q row from GLOBAL qtab at wave-uniform address) ---
    int curu = __builtin_amdgcn_readfirstlane(cur);
    const float4* q4 = (const float4*)(qhb + (curu << 8));
    v2f s00 = {0.f, 0.f}, s01 = {0.f, 0.f}, s10 = {0.f, 0.f}, s11 = {0.f, 0.f};
#pragma unroll
    for (int dd = 0; dd < 8; ++dd) {
      float4 qv = q4[dd];
      v2f qa = {qv.x, qv.y}, qb = {qv.z, qv.w};
      pkfma(s00, qa, k0p[2 * dd]);
      pkfma(s01, qb, k0p[2 * dd + 1]);
      pkfma(s10, qa, k1p[2 * dd]);
      pkfma(s11, qb, k1p[2 * dd + 1]);
    }
    float slo = vis_lo ? NEG : ((s00.x + s00.y) + (s01.x + s01.y)) * SCALE;
    float shi = vis_hi ? NEG : ((s10.x + s10.y) + (s11.x + s11.y)) * SCALE;
    // --- softmax (in-wave; division deferred; DPP-only reductions) ---
    float m = wred_max(fmaxf(slo, shi));
    float elo = expf(slo - m), ehi = expf(shi - m);
    at_s[h * 128 + j] = elo;
    at_s[h * 128 + 64 + j] = ehi;
    float inv = 1.0f / wred_sum(elo + ehi);
    // --- ctx for e_own over n-half (wave-local LDS read, no barrier) ---
    const float4* a4 = (const float4*)(at_s + h * 128 + nh * 64);
    v2f c0 = {0.f, 0.f}, c1 = {0.f, 0.f};
#pragma unroll
    for (int mm = 0; mm < 16; ++mm) {
      float4 av = a4[mm];
      v2f aa = {av.x, av.y}, ab = {av.z, av.w};
      pkfma(c0, aa, vp[2 * mm]);
      pkfma(c1, ab, vp[2 * mm + 1]);
    }
    float c = (c0.x + c0.y) + (c1.x + c1.y);
    c += __shfl_xor(c, 32);     // combine n-halves (lanes j, j^32 share e_own)
    c *= inv;
    if (j < 32) ctx_s[h * 32 + j] = c;
    // --- z partial for head-slice (wave-local broadcast read) ---
    const float4* cx4 = (const float4*)(ctx_s + h * 32);
    v2f z00 = {0.f, 0.f}, z01 = {0.f, 0.f}, z10 = {0.f, 0.f}, z11 = {0.f, 0.f};
#pragma unroll
    for (int ee = 0; ee < 8; ++ee) {
      float4 cv = cx4[ee];
      v2f ca = {cv.x, cv.y}, cb = {cv.z, cv.w};
      pkfma(z00, ca, l0p[2 * ee]);
      pkfma(z01, cb, l0p[2 * ee + 1]);
      pkfma(z10, ca, l1p[2 * ee]);
      pkfma(z11, cb, l1p[2 * ee + 1]);
    }
    float* zpw = zp + (it & 1) * 1536;
    zpw[rof0 + csw] = (z00.x + z00.y) + (z01.x + z01.y);
    zpw[rof1 + csw] = (z10.x + z10.y) + (z11.x + z11.y);
    __syncthreads();   // the ONLY barrier per step

    // --- phase C: assemble z via 2x b128/half + argmax; LSE wave 0 only ---
    const float4* zr0 = (const float4*)(zpw + rof0);
    const float4* zr1 = (const float4*)(zpw + rof1);
    float4 za = zr0[0], zb = zr0[1], zc = zr1[0], zd = zr1[1];
    float zlo = cv_lo + ((za.x + za.y) + (za.z + za.w)) + ((zb.x + zb.y) + (zb.z + zb.w));
    float zhi = cv_hi + ((zc.x + zc.y) + (zc.z + zc.w)) + ((zd.x + zd.y) + (zd.z + zd.w));
    float zmlo = vis_lo ? -1e30f : zlo;
    float zmhi = vis_hi ? -1e30f : zhi;
    float vmax = wred_max(fmaxf(zmlo, zmhi));
    unsigned long long blo = __ballot(zmlo == vmax);
    int action;
    if (blo) action = __ffsll((unsigned long long)blo) - 1;
    else     action = 63 + __ffsll((unsigned long long)__ballot(zmhi == vmax));
    if (h == 0) {
      float lmax = CLIPV * tanhf(vmax * SCALE);
      float tlo = vis_lo ? 0.f : expf(CLIPV * tanhf(zlo * SCALE) - 10.0f);
      float thi = vis_hi ? 0.f : expf(CLIPV * tanhf(zhi * SCALE) - 10.0f);
      float S = wred_sum(tlo + thi);
      lp += lmax - 10.0f - logf(S);
    }
    cur = action;
    vis_lo |= (action == j);
    vis_hi |= (action == j + 64);
  }
  if (lt == 0) out[b] = lp;
}

// ---------------------------------------------------------------- K4b: fallback rollout (verbatim R14)
__global__ __attribute__((amdgpu_flat_work_group_size(512, 512), amdgpu_waves_per_eu(2, 2)))
void k_roll(const float* __restrict__ emb, const float* __restrict__ Wstep,
            const float* __restrict__ kT, const float* __restrict__ vv_,
            const float* __restrict__ lkT,
            const float* __restrict__ qbase, const float* __restrict__ cvec,
            float* __restrict__ out) {
  int lt = threadIdx.x;
  int b = blockIdx.x;
  int h = lt >> 6;
  int j = lt & 63;

  __shared__ float sq_lds[128 * 260];
  __shared__ float work[6144];
  float* at_s  = work;
  float* ctx_s = work + 1024;
  float* zp    = work + 1280;

  {
    float* At = work;
    float* Bs = work + 2048;
    const float4* eb4 = (const float4*)(emb + (size_t)b * 32768);
    const float* W2 = Wstep + 65536;
    int n0 = (lt & 31) * 4;
    int e0 = (lt >> 5) * 16;
    float acc[4][16];
#pragma unroll
    for (int i = 0; i < 4; ++i)
#pragma unroll
      for (int jj = 0; jj < 16; ++jj) acc[i][jj] = 0.f;

    for (int gc = 0; gc < 16; ++gc) {
      {
        int n = lt & 127, q4g = lt >> 7;
        float4 a = eb4[n * 64 + gc * 4 + q4g];
        At[(q4g * 4 + 0) * 128 + n] = a.x;
        At[(q4g * 4 + 1) * 128 + n] = a.y;
        At[(q4g * 4 + 2) * 128 + n] = a.z;
        At[(q4g * 4 + 3) * 128 + n] = a.w;
      }
      {
        const float4* w4 = (const float4*)(W2 + gc * 16 * 256);
        ((float4*)Bs)[lt] = w4[lt];
        ((float4*)Bs)[lt + 512] = w4[lt + 512];
      }
      __syncthreads();
#pragma unroll
      for (int gi = 0; gi < 16; ++gi) {
        float4 a4 = *(const float4*)(At + gi * 128 + n0);
        const float4* bp = (const float4*)(Bs + gi * 256 + e0);
        float4 b0 = bp[0], b1 = bp[1], b2 = bp[2], b3 = bp[3];
        float av[4] = {a4.x, a4.y, a4.z, a4.w};
        float bv[16] = {b0.x, b0.y, b0.z, b0.w, b1.x, b1.y, b1.z, b1.w,
                        b2.x, b2.y, b2.z, b2.w, b3.x, b3.y, b3.z, b3.w};
#pragma unroll
        for (int i = 0; i < 4; ++i)
#pragma unroll
          for (int jj = 0; jj < 16; ++jj) acc[i][jj] += av[i] * bv[jj];
      }
      __syncthreads();
    }
    const float* qb = qbase + (size_t)b * 256;
    float qbr[16];
#pragma unroll
    for (int jj = 0; jj < 16; ++jj) qbr[jj] = qb[e0 + jj];
#pragma unroll
    for (int i = 0; i < 4; ++i)
#pragma unroll
      for (int jj = 0; jj < 16; ++jj)
        sq_lds[(n0 + i) * 260 + e0 + jj] = acc[i][jj] + qbr[jj];
  }
  __syncthreads();
  __builtin_amdgcn_sched_barrier(0);

  const float* kTb = kT + (size_t)b * 32768;
  const float* vb  = vv_ + (size_t)b * 32768;
  const float* lTb = lkT + (size_t)b * 32768;

  v2f k0p[16], k1p[16];
#pragma unroll
  for (int d = 0; d < 16; ++d) {
    k0p[d] = (v2f){kTb[(h * 32 + 2 * d) * 128 + j],      kTb[(h * 32 + 2 * d + 1) * 128 + j]};
    k1p[d] = (v2f){kTb[(h * 32 + 2 * d) * 128 + j + 64], kTb[(h * 32 + 2 * d + 1) * 128 + j + 64]};
    asm("" : "+v"(k0p[d]));
    asm("" : "+v"(k1p[d]));
  }
  int e_own = h * 32 + (j & 31), nh = j >> 5;
  v2f vp[32];
#pragma unroll
  for (int m = 0; m < 32; ++m) {
    vp[m] = (v2f){vb[(nh * 64 + 2 * m) * 256 + e_own], vb[(nh * 64 + 2 * m + 1) * 256 + e_own]};
    asm("" : "+v"(vp[m]));
  }
  v2f l0p[16], l1p[16];
#pragma unroll
  for (int e = 0; e < 16; ++e) {
    l0p[e] = (v2f){lTb[(h * 32 + 2 * e) * 128 + j],      lTb[(h * 32 + 2 * e + 1) * 128 + j]};
    l1p[e] = (v2f){lTb[(h * 32 + 2 * e) * 128 + j + 64], lTb[(h * 32 + 2 * e + 1) * 128 + j + 64]};
    asm("" : "+v"(l0p[e]));
    asm("" : "+v"(l1p[e]));
  }
  float cv_lo = cvec[b * 128 + j];
  float cv_hi = cvec[b * 128 + j + 64];
  int vis_lo = (j == 0) ? 1 : 0, vis_hi = 0;
  int cur = 0;
  float lp = 0.f;
  int rof0 = j * 12;
  int rof1 = rof0 + 768;
  int csw  = h ^ ((j >> 2) & 7);

#pragma unroll 1
  for (int it = 0; it < N_ - 1; ++it) {
    const float4* q4 = (const float4*)(sq_lds + cur * 260 + h * 32);
    v2f s00 = {0.f, 0.f}, s01 = {0.f, 0.f}, s10 = {0.f, 0.f}, s11 = {0.f, 0.f};
#pragma unroll
    for (int dd = 0; dd < 8; ++dd) {
      float4 qv = q4[dd];
      v2f qa = {qv.x, qv.y}, qb = {qv.z, qv.w};
      pkfma(s00, qa, k0p[2 * dd]);
      pkfma(s01, qb, k0p[2 * dd + 1]);
      pkfma(s10, qa, k1p[2 * dd]);
      pkfma(s11, qb, k1p[2 * dd + 1]);
    }
    float slo = vis_lo ? NEG : ((s00.x + s00.y) + (s01.x + s01.y)) * SCALE;
    float shi = vis_hi ? NEG : ((s10.x + s10.y) + (s11.x + s11.y)) * SCALE;
    float m = wred_max(fmaxf(slo, shi));
    float elo = expf(slo - m), ehi = expf(shi - m);
    at_s[h * 128 + j] = elo;
    at_s[h * 128 + 64 + j] = ehi;
    float inv = 1.0f / wred_sum(elo + ehi);
    const float4* a4 = (const float4*)(at_s + h * 128 + nh * 64);
    v2f c0 = {0.f, 0.f}, c1 = {0.f, 0.f};
#pragma unroll
    for (int mm = 0; mm < 16; ++mm) {
      float4 av = a4[mm];
      v2f aa = {av.x, av.y}, ab = {av.z, av.w};
      pkfma(c0, aa, vp[2 * mm]);
      pkfma(c1, ab, vp[2 * mm + 1]);
    }
    float c = (c0.x + c0.y) + (c1.x + c1.y);
    c += __shfl_xor(c, 32);
    c *= inv;
    if (j < 32) ctx_s[h * 32 + j] = c;
    const float4* cx4 = (const float4*)(ctx_s + h * 32);
    v2f z00 = {0.f, 0.f}, z01 = {0.f, 0.f}, z10 = {0.f, 0.f}, z11 = {0.f, 0.f};
#pragma unroll
    for (int ee = 0; ee < 8; ++ee) {
      float4 cv = cx4[ee];
      v2f ca = {cv.x, cv.y}, cb = {cv.z, cv.w};
      pkfma(z00, ca, l0p[2 * ee]);
      pkfma(z01, cb, l0p[2 * ee + 1]);
      pkfma(z10, ca, l1p[2 * ee]);
      pkfma(z11, cb, l1p[2 * ee + 1]);
    }
    float* zpw = zp + (it & 1) * 1536;
    zpw[rof0 + csw] = (z00.x + z00.y) + (z01.x + z01.y);
    zpw[rof1 + csw] = (z10.x + z10.y) + (z11.x + z11.y);
    __syncthreads();

    const float4* zr0 = (const float4*)(zpw + rof0);
    const float4* zr1 = (const float4*)(zpw + rof1);
    float4 za = zr0[0], zb = zr0[1], zc = zr1[0], zd = zr1[1];
    float zlo = cv_lo + ((za.x + za.y) + (za.z + za.w)) + ((zb.x + zb.y) + (zb.z + zb.w));
    float zhi = cv_hi + ((zc.x + zc.y) + (zc.z + zc.w)) + ((zd.x + zd.y) + (zd.z + zd.w));
    float zmlo = vis_lo ? -1e30f : zlo;
    float zmhi = vis_hi ? -1e30f : zhi;
    float vmax = wred_max(fmaxf(zmlo, zmhi));
    unsigned long long blo = __ballot(zmlo == vmax);
    int action;
    if (blo) action = __ffsll((unsigned long long)blo) - 1;
    else     action = 63 + __ffsll((unsigned long long)__ballot(zmhi == vmax));
    if (h == 0) {
      float lmax = CLIPV * tanhf(vmax * SCALE);
      float tlo = vis_lo ? 0.f : expf(CLIPV * tanhf(zlo * SCALE) - 10.0f);
      float thi = vis_hi ? 0.f : expf(CLIPV * tanhf(zhi * SCALE) - 10.0f);
      float S = wred_sum(tlo + thi);
      lp += lmax - 10.0f - logf(S);
    }
    cur = action;
    vis_lo |= (action == j);
    vis_hi |= (action == j + 64);
  }
  if (lt == 0) out[b] = lp;
}

// ---------------------------------------------------------------- launch
extern "C" void kernel_launch(void* const* d_in, const int* in_sizes, int n_in,
                              void* d_out, int out_size, void* d_ws, size_t ws_size,
                              hipStream_t stream) {
  (void)in_sizes; (void)n_in; (void)out_size;
  const float* emb   = (const float*)d_in[0];
  const float* Wqkv  = (const float*)d_in[1];
  const float* bqkv  = (const float*)d_in[2];
  const float* Wfix  = (const float*)d_in[3];
  const float* bfix  = (const float*)d_in[4];
  const float* Wstep = (const float*)d_in[5];
  const float* bstep = (const float*)d_in[6];
  const float* Wmlp  = (const float*)d_in[7];
  const float* bmlp  = (const float*)d_in[8];
  float* out = (float*)d_out;
  float* ws = (float*)d_ws;

  const size_t NBE = (size_t)B_ * N_ * E_;  // 16,777,216 floats
  float* kk_    = ws;                  // kT
  float* vv_    = ws + NBE;            // v
  float* lk2    = ws + 2 * NBE;        // lkT
  float* qbase  = ws + 3 * NBE;        // 131072
  float* cvec   = qbase + 131072;      // 65536
  float* Wc     = cvec + 65536;        // 65536
  float* bc     = Wc + 65536;          // 256
  float* wc2    = bc + 256;            // 256
  float* cconst = wc2 + 256;           // (64 pad)
  size_t qoff   = 3 * NBE + 262720;
  float* qtab   = ws + qoff;           // NBE floats (optional)
  int use_qtab  = (ws_size >= (qoff + NBE) * sizeof(float)) ? 1 : 0;

  hipLaunchKernelGGL(k0_prep, dim3(257), dim3(256), 0, stream,
                     Wqkv, bqkv, Wmlp, bmlp, Wc, bc, wc2, cconst);
  hipLaunchKernelGGL(k_qbase, dim3(512), dim3(256), 0, stream,
                     emb, Wfix, bfix, Wstep, bstep, qbase);
  hipLaunchKernelGGL(k_c, dim3(256), dim3(256), 0, stream,
                     emb, wc2, cconst, cvec);
  hipLaunchKernelGGL(k_gemm, dim3(1024), dim3(256), 0, stream,
                     emb, Wqkv, bqkv, Wc, bc, Wstep, qbase,
                     kk_, vv_, lk2, qtab, use_qtab ? 8 : 6, 0b0101);
  if (use_qtab) {
    hipLaunchKernelGGL(k_rollq, dim3(512), dim3(512), 0, stream,
                       kk_, vv_, lk2, cvec, qtab, out);
  } else {
    hipLaunchKernelGGL(k_roll, dim3(512), dim3(512), 0, stream,
                       emb, Wstep, kk_, vv_, lk2, qbase, cvec, out);
  }
}